// Round 9
// baseline (129.857 us; speedup 1.0000x reference)
//
#include <hip/hip_runtime.h>

#define NH 6
#define HEAD_DIM 32
#define CCH 192
#define HH 56
#define WW 56
#define HWSZ (HH * WW)            // 3136
#define KPOS 9
#define SCALE 0.17677669529663687f  // 32^-0.5
#define XPAD 61                   // conflict-free layout (R5-proven, 0 conflicts)
#define ROWSZ (HEAD_DIM * XPAD)   // 1952 floats per staged row-plane
#define NR 4                      // staged rows {y0-2, y0, y0+2, y0+4}
#define STRIPS 14                 // strips of 2 same-parity rows

// Block = (bh, parity, strip): outputs rows y0 and y0+2. ONE 31.2KB LDS buffer
// used twice: stage k rows -> QK both rows -> barrier -> commit prefetched v
// (loads issued before QK, in flight behind ~3K cyc compute) -> PV both rows.
// 5 blocks/CU (20 waves), 3 barriers/block, 1344 blocks (churn balances CUs).
__global__ __launch_bounds__(256, 5) void dilate_attn_v9(
    const float* __restrict__ q,
    const float* __restrict__ k,
    const float* __restrict__ v,
    float* __restrict__ out)
{
    __shared__ float buf[NR * ROWSZ];     // 31,232 B

    const int bh     = blockIdx.x % 48;   // bh fastest: reuse partners same XCD
    const int r1     = blockIdx.x / 48;   // 0..27
    const int parity = r1 / STRIPS;
    const int si     = r1 % STRIPS;
    const int y0     = parity + 4 * si;   // outputs y0, y0+2
    const int t      = threadIdx.x;

    const size_t plane = (size_t)bh * HEAD_DIM * HWSZ;
    const int px = t >> 2;                // 0..63 (valid < 56)
    const int c  = t & 3;                 // dim-octet
    const bool active = px < WW;

    // staging maps: 7 elems/thread per row (7*256 = 1792 = 32*56)
    int goff[7], aoff[7];
#pragma unroll
    for (int i = 0; i < 7; i++) {
        const int e = t + 256 * i;
        const int d = e / WW;
        const int x = e - d * WW;
        goff[i] = d * HWSZ + x;
        aoff[i] = d * XPAD + x + 2;
    }

    // row validity + clamped row offsets for the 4 staged rows
    int   roff[NR];
    bool  rok[NR];
#pragma unroll
    for (int r = 0; r < NR; r++) {
        const int ky = y0 - 2 + 2 * r;
        rok[r]  = (ky >= 0) && (ky < HH);
        roff[r] = (rok[r] ? ky : 0) * WW;
    }

    // ---- issue q loads for both output rows (fully independent) ----
    float qa[8], qb[8];
    if (active) {
        const float* q0 = q + plane + (size_t)(8 * c) * HWSZ + (size_t)y0 * WW + px;
        const float* q1 = q0 + 2 * WW;
#pragma unroll
        for (int j = 0; j < 8; j++) { qa[j] = q0[j * HWSZ]; qb[j] = q1[j * HWSZ]; }
    }

    // ---- stage k: 28 loads -> regs -> LDS; pads written once (v keeps them) ----
    {
        float kpre[NR][7];
#pragma unroll
        for (int r = 0; r < NR; r++)
#pragma unroll
            for (int i = 0; i < 7; i++)
                kpre[r][i] = rok[r] ? k[plane + roff[r] + goff[i]] : 0.0f;
#pragma unroll
        for (int r = 0; r < NR; r++)
#pragma unroll
            for (int i = 0; i < 7; i++)
                buf[r * ROWSZ + aoff[i]] = kpre[r][i];
    }
    // zero-pad columns x' in {0,1,58,59}: 4 slots * 32 d * 4 cols = 512 = 2/thread
#pragma unroll
    for (int ii = 0; ii < 2; ii++) {
        const int e  = t + 256 * ii;
        const int r  = e >> 7;
        const int rr = e & 127;
        const int d  = rr >> 2;
        const int xc = rr & 3;
        const int xp = (xc < 2) ? xc : (56 + xc);
        buf[r * ROWSZ + d * XPAD + xp] = 0.0f;
    }
    __syncthreads();                      // barrier 1: k visible

    // ---- issue v prefetch (28 loads, in flight behind QK compute) ----
    float vpre[NR][7];
#pragma unroll
    for (int r = 0; r < NR; r++)
#pragma unroll
        for (int i = 0; i < 7; i++)
            vpre[r][i] = rok[r] ? v[plane + roff[r] + goff[i]] : 0.0f;

    // ---- QK for both rows; softmax -> weights (kept in regs) ----
    float w0[KPOS], w1[KPOS];
    if (active) {
#pragma unroll
        for (int w2 = 0; w2 < 2; w2++) {
            float* lg = w2 ? w1 : w0;
            const float* qr = w2 ? qb : qa;
#pragma unroll
            for (int rp = 0; rp < 3; rp++) {
                const float* kr = buf + (w2 + rp) * ROWSZ + (8 * c) * XPAD + px;
                float a0 = 0.f, a1 = 0.f, a2 = 0.f;
#pragma unroll
                for (int j = 0; j < 8; j++) {
                    const float* p = kr + j * XPAD;
                    const float qj = qr[j];
                    a0 = fmaf(qj, p[0], a0);
                    a1 = fmaf(qj, p[2], a1);
                    a2 = fmaf(qj, p[4], a2);
                }
                lg[3 * rp + 0] = a0;
                lg[3 * rp + 1] = a1;
                lg[3 * rp + 2] = a2;
            }
#pragma unroll
            for (int kk = 0; kk < KPOS; kk++) {
                float s = lg[kk];
                s += __shfl_xor(s, 1);
                s += __shfl_xor(s, 2);
                lg[kk] = s * SCALE;
            }
            float m = lg[0];
#pragma unroll
            for (int kk = 1; kk < KPOS; kk++) m = fmaxf(m, lg[kk]);
            float ssum = 0.f;
#pragma unroll
            for (int kk = 0; kk < KPOS; kk++) {
                lg[kk] = __expf(lg[kk] - m);
                ssum += lg[kk];
            }
            const float inv = 1.f / ssum;
#pragma unroll
            for (int kk = 0; kk < KPOS; kk++) lg[kk] *= inv;
        }
    }
    __syncthreads();                      // barrier 2: all k reads done

    // ---- commit v into the same buffer ----
#pragma unroll
    for (int r = 0; r < NR; r++)
#pragma unroll
        for (int i = 0; i < 7; i++)
            buf[r * ROWSZ + aoff[i]] = vpre[r][i];
    __syncthreads();                      // barrier 3: v visible

    // ---- PV + store, both rows ----
    if (active) {
        const int h = bh % NH;
        const int b = bh / NH;
#pragma unroll
        for (int w2 = 0; w2 < 2; w2++) {
            const float* w = w2 ? w1 : w0;
            float acc[8];
#pragma unroll
            for (int j = 0; j < 8; j++) acc[j] = 0.f;
#pragma unroll
            for (int rp = 0; rp < 3; rp++) {
                const float* vr = buf + (w2 + rp) * ROWSZ + (8 * c) * XPAD + px;
                const float wa = w[3 * rp + 0];
                const float wb = w[3 * rp + 1];
                const float wc = w[3 * rp + 2];
#pragma unroll
                for (int j = 0; j < 8; j++) {
                    const float* p = vr + j * XPAD;
                    float a = acc[j];
                    a = fmaf(wa, p[0], a);
                    a = fmaf(wb, p[2], a);
                    a = fmaf(wc, p[4], a);
                    acc[j] = a;
                }
            }
            const int y = y0 + 2 * w2;
            float* ob = out + ((size_t)((b * HH + y) * WW + px)) * CCH
                            + h * HEAD_DIM + 8 * c;
            reinterpret_cast<float4*>(ob)[0] = make_float4(acc[0], acc[1], acc[2], acc[3]);
            reinterpret_cast<float4*>(ob)[1] = make_float4(acc[4], acc[5], acc[6], acc[7]);
        }
    }
}

extern "C" void kernel_launch(void* const* d_in, const int* in_sizes, int n_in,
                              void* d_out, int out_size, void* d_ws, size_t ws_size,
                              hipStream_t stream) {
    const float* q = (const float*)d_in[0];
    const float* k = (const float*)d_in[1];
    const float* v = (const float*)d_in[2];
    float* out = (float*)d_out;

    const int blocks = 48 * 2 * STRIPS;   // 1344
    dilate_attn_v9<<<blocks, 256, 0, stream>>>(q, k, v, out);
}